// Round 1
// baseline (121.187 us; speedup 1.0000x reference)
//
#include <hip/hip_runtime.h>

// VectorQuantiser on MI355X.
// x: [32,32,32,256] f32, mean[1], stddev[1], emb: [64,512] f32 (d-major).
// flat row n = (b*256 + c)*16 + g, element d -> x[b, 2g + (d>>5), d&31, c].
// Per WG: (b, g, c-half): rows = 128 c-values, all 512 codes in 4 chunks of 128.
// Output0: quantised [32,32,32,256] f32 at d_out[0..8388607]
// Output1: indices (as f32) at d_out[8388608 .. 8519679]

#define NELEM0 8388608

__global__ __launch_bounds__(256, 2)
void vq_kernel(const float* __restrict__ x, const float* __restrict__ meanp,
               const float* __restrict__ sdp, const float* __restrict__ emb,
               float* __restrict__ out, float* __restrict__ outIdx)
{
    __shared__ float xs[64 * 128];   // xs[d][c']
    __shared__ float es[64 * 128];   // es[d][k'] ; reused as reduce buffer at the end
    __shared__ float x2[128];
    __shared__ float e2[128];
    __shared__ int   idxf[128];

    const int tid  = threadIdx.x;
    const int blk  = blockIdx.x;
    const int half = blk & 1;
    const int g    = (blk >> 1) & 15;
    const int b    = blk >> 5;
    const int c0   = half * 128;

    const float mean = meanp[0];
    const float sd   = sdp[0];
    const bool  sdz  = (sd == 0.0f);
    const float safe = sdz ? 1.0f : sd;

    // contiguous 64KB slab base: linear = xbase + d*256 + c
    const size_t xbase = ((size_t)(b * 32 + 2 * g) * 32) * 256;

    // ---- stage xs[d][c'] = divide_no_nan(x, sd) - mean ----
    #pragma unroll
    for (int i = 0; i < 8; ++i) {
        int idx4 = i * 256 + tid;          // 0..2047 float4 units (64 x 32)
        int d    = idx4 >> 5;
        int c4   = idx4 & 31;
        const float4 v = *reinterpret_cast<const float4*>(
            &x[xbase + (size_t)d * 256 + c0 + c4 * 4]);
        float4 s;
        s.x = (sdz ? 0.0f : v.x / safe) - mean;
        s.y = (sdz ? 0.0f : v.y / safe) - mean;
        s.z = (sdz ? 0.0f : v.z / safe) - mean;
        s.w = (sdz ? 0.0f : v.w / safe) - mean;
        *reinterpret_cast<float4*>(&xs[d * 128 + c4 * 4]) = s;
    }
    __syncthreads();

    // ---- x2[c'] = sum_d xs[d][c']^2 ----
    if (tid < 128) {
        float s = 0.0f;
        for (int d = 0; d < 64; ++d) { float v = xs[d * 128 + tid]; s = fmaf(v, v, s); }
        x2[tid] = s;
    }

    const int tr = tid & 15;      // row group
    const int tk = tid >> 4;      // code group
    const int r0 = tr * 8;
    const int k0 = tk * 8;

    float bestv[8];
    int   besti[8];
    #pragma unroll
    for (int r = 0; r < 8; ++r) { bestv[r] = 3.4e38f; besti[r] = 0; }

    for (int ch = 0; ch < 4; ++ch) {
        __syncthreads();   // es reuse from previous chunk + x2 visibility on ch==0

        // ---- stage es[d][k'] = emb[d][ch*128 + k'] ----
        #pragma unroll
        for (int i = 0; i < 8; ++i) {
            int idx4 = i * 256 + tid;
            int d    = idx4 >> 5;
            int k4   = idx4 & 31;
            const float4 v = *reinterpret_cast<const float4*>(
                &emb[(size_t)d * 512 + ch * 128 + k4 * 4]);
            *reinterpret_cast<float4*>(&es[d * 128 + k4 * 4]) = v;
        }
        __syncthreads();

        // ---- e2[k'] = sum_d es[d][k']^2 ----
        if (tid < 128) {
            float s = 0.0f;
            for (int d = 0; d < 64; ++d) { float v = es[d * 128 + tid]; s = fmaf(v, v, s); }
            e2[tid] = s;
        }
        __syncthreads();

        // ---- register-tiled dot: acc[r][k] = sum_d xs[d][r0+r] * es[d][k0+k] ----
        float acc[8][8];
        #pragma unroll
        for (int r = 0; r < 8; ++r)
            #pragma unroll
            for (int k = 0; k < 8; ++k) acc[r][k] = 0.0f;

        #pragma unroll 4
        for (int d = 0; d < 64; ++d) {
            float4 xa = *reinterpret_cast<const float4*>(&xs[d * 128 + r0]);
            float4 xb = *reinterpret_cast<const float4*>(&xs[d * 128 + r0 + 4]);
            float4 ea = *reinterpret_cast<const float4*>(&es[d * 128 + k0]);
            float4 eb = *reinterpret_cast<const float4*>(&es[d * 128 + k0 + 4]);
            float xv[8] = {xa.x, xa.y, xa.z, xa.w, xb.x, xb.y, xb.z, xb.w};
            float ev[8] = {ea.x, ea.y, ea.z, ea.w, eb.x, eb.y, eb.z, eb.w};
            #pragma unroll
            for (int r = 0; r < 8; ++r)
                #pragma unroll
                for (int k = 0; k < 8; ++k)
                    acc[r][k] = fmaf(xv[r], ev[k], acc[r][k]);
        }

        // ---- dist = (x2 + e2) - 2*dot (mirror np eval order), running argmin ----
        #pragma unroll
        for (int r = 0; r < 8; ++r) {
            const float xr = x2[r0 + r];
            #pragma unroll
            for (int k = 0; k < 8; ++k) {
                float t = xr + e2[k0 + k];
                float v = t - 2.0f * acc[r][k];
                int   kg = ch * 128 + k0 + k;          // ascending across (ch,k)
                if (v < bestv[r]) { bestv[r] = v; besti[r] = kg; }  // first-occurrence
            }
        }
    }

    // ---- cross-group lexicographic (value, index) min via LDS (reuse es) ----
    __syncthreads();
    float2* red = reinterpret_cast<float2*>(es);   // red[row][16 groups]
    #pragma unroll
    for (int r = 0; r < 8; ++r) {
        float2 p; p.x = bestv[r]; p.y = __int_as_float(besti[r]);
        red[(r0 + r) * 16 + tk] = p;
    }
    __syncthreads();
    if (tid < 128) {
        float bv = 3.4e38f; int bi = 0x7fffffff;
        for (int gk = 0; gk < 16; ++gk) {
            float2 p = red[tid * 16 + gk];
            int i2 = __float_as_int(p.y);
            if (p.x < bv || (p.x == bv && i2 < bi)) { bv = p.x; bi = i2; }
        }
        idxf[tid] = bi;
    }
    __syncthreads();

    // ---- outputs ----
    // out0[xbase + d*256 + c0 + c'] = x + (((emb[d][k] + mean) * sd) - x)
    for (int i = 0; i < 32; ++i) {
        int lin = i * 256 + tid;         // 0..8191
        int cp  = lin & 127;
        int d   = lin >> 7;
        int k   = idxf[cp];
        float q  = emb[(size_t)d * 512 + k];
        q = (q + mean) * sd;
        size_t go = xbase + (size_t)d * 256 + c0 + cp;
        float xv = x[go];
        out[go] = xv + (q - xv);         // straight-through, mirror fp order
    }
    // out1: n = (b*256 + c)*16 + g, written as float (harness reads whole buf as f32)
    if (tid < 128) {
        int n = (b * 256 + c0 + tid) * 16 + g;
        outIdx[n] = (float)idxf[tid];
    }
}

extern "C" void kernel_launch(void* const* d_in, const int* in_sizes, int n_in,
                              void* d_out, int out_size, void* d_ws, size_t ws_size,
                              hipStream_t stream) {
    const float* x    = (const float*)d_in[0];
    const float* mean = (const float*)d_in[1];
    const float* sd   = (const float*)d_in[2];
    const float* emb  = (const float*)d_in[3];
    float* out    = (float*)d_out;
    float* outIdx = out + NELEM0;

    vq_kernel<<<dim3(1024), dim3(256), 0, stream>>>(x, mean, sd, emb, out, outIdx);
}